// Round 1
// baseline (485.032 us; speedup 1.0000x reference)
//
#include <hip/hip_runtime.h>

#define RES 64
#define CHANNEL 32
#define DIM 512
#define BATCH 32
#define ROWS (RES * RES * CHANNEL)   // 131072

#define BM 256        // rows per block tile
#define BK 32         // k-chunk
#define TM 4          // rows per thread
#define TN 8          // batch cols per thread
#define NCHUNK (DIM / BK)  // 16

// Kernel 1: scaledT[d][b] = L[d] * style[b][d]   (512 x 32 floats = 64 KiB in d_ws)
__global__ void scale_kernel(const float* __restrict__ style,
                             const float* __restrict__ L,
                             float* __restrict__ scaledT) {
    int i = blockIdx.x * 256 + threadIdx.x;   // 0 .. 16383
    int d = i >> 5;
    int b = i & 31;
    scaledT[d * 32 + b] = L[d] * style[b * DIM + d];
}

// Kernel 2: out[b*ROWS + m] = sum_d U[m*DIM+d] * scaledT[d*32+b] + mu[m]
__global__ __launch_bounds__(256, 2) void eigen_kernel(
    const float* __restrict__ U,
    const float* __restrict__ mu,
    const float* __restrict__ scaledT,
    float* __restrict__ out) {

    // Double-buffered U tile: [2][BM rows][BK floats], XOR-swizzled to kill bank conflicts.
    __shared__ float Ut[2][BM * BK];   // 2 x 32 KiB = 64 KiB

    const int tid = threadIdx.x;
    const int l  = tid & 63;                 // row-thread within wave (0..63)
    const int cg = tid >> 6;                 // col group == wave id (0..3)
    const int b0 = __builtin_amdgcn_readfirstlane(cg * TN);  // wave-uniform -> SGPR path for scaled
    const int sw = (l & 7) * 4;              // bank swizzle for this thread's rows
    const int R0 = blockIdx.x * BM;

    float acc[TM][TN];
#pragma unroll
    for (int r = 0; r < TM; ++r)
#pragma unroll
        for (int b = 0; b < TN; ++b) acc[r][b] = 0.0f;

    // ---- staging geometry (same every chunk) ----
    // piece j (j=0..7): flat float4 index f = j*256 + tid over the 256x32 tile
    //   row = f>>3 = j*32 + (tid>>3),  dd4 = (f&7) -> d offset (tid&7)*4
    const int srow_base = tid >> 3;          // + j*32
    const int sdd       = (tid & 7) * 4;
    // LDS swizzled offset: row*BK + (sdd ^ ((row&7)*4)); row&7 == (tid>>3)&7 (j*32 drops out)
    const int lds_sw    = sdd ^ (((tid >> 3) & 7) * 4);

    float4 pre[8];

    // prologue: load + store chunk 0
#pragma unroll
    for (int j = 0; j < 8; ++j) {
        int row = srow_base + j * 32;
        pre[j] = *(const float4*)&U[(size_t)(R0 + row) * DIM + sdd];
    }
#pragma unroll
    for (int j = 0; j < 8; ++j) {
        int row = srow_base + j * 32;
        *(float4*)&Ut[0][row * BK + lds_sw] = pre[j];
    }
    __syncthreads();

    const float4* s4 = (const float4*)scaledT;

#pragma unroll 1
    for (int c = 0; c < NCHUNK; ++c) {
        const int cur = c & 1;

        // issue global prefetch of chunk c+1 (stays in flight during compute)
        if (c + 1 < NCHUNK) {
#pragma unroll
            for (int j = 0; j < 8; ++j) {
                int row = srow_base + j * 32;
                pre[j] = *(const float4*)&U[(size_t)(R0 + row) * DIM + (c + 1) * BK + sdd];
            }
        }

        const float* ut = &Ut[cur][0];
        const int dbase = c * BK;

#pragma unroll
        for (int dd = 0; dd < BK; dd += 4) {
            float4 u[TM];
#pragma unroll
            for (int r = 0; r < TM; ++r) {
                int tr = l + 64 * r;
                u[r] = *(const float4*)&ut[tr * BK + (dd ^ sw)];
            }
#pragma unroll
            for (int j = 0; j < 4; ++j) {
                // wave-uniform scaled loads (SGPR/broadcast): 8 floats for this wave's b-slice
                float4 sA = s4[(size_t)(dbase + dd + j) * 8 + (b0 >> 2)];
                float4 sB = s4[(size_t)(dbase + dd + j) * 8 + (b0 >> 2) + 1];
#pragma unroll
                for (int r = 0; r < TM; ++r) {
                    float uv = (j == 0) ? u[r].x : (j == 1) ? u[r].y : (j == 2) ? u[r].z : u[r].w;
                    acc[r][0] += uv * sA.x;
                    acc[r][1] += uv * sA.y;
                    acc[r][2] += uv * sA.z;
                    acc[r][3] += uv * sA.w;
                    acc[r][4] += uv * sB.x;
                    acc[r][5] += uv * sB.y;
                    acc[r][6] += uv * sB.z;
                    acc[r][7] += uv * sB.w;
                }
            }
        }

        // write prefetched chunk into the other buffer
        if (c + 1 < NCHUNK) {
#pragma unroll
            for (int j = 0; j < 8; ++j) {
                int row = srow_base + j * 32;
                *(float4*)&Ut[cur ^ 1][row * BK + lds_sw] = pre[j];
            }
        }
        __syncthreads();
    }

    // epilogue: out[b][m] = acc + mu[m]
#pragma unroll
    for (int r = 0; r < TM; ++r) {
        int m = R0 + l + 64 * r;
        float muv = mu[m];
#pragma unroll
        for (int bb = 0; bb < TN; ++bb) {
            out[(size_t)(b0 + bb) * ROWS + m] = acc[r][bb] + muv;
        }
    }
}

extern "C" void kernel_launch(void* const* d_in, const int* in_sizes, int n_in,
                              void* d_out, int out_size, void* d_ws, size_t ws_size,
                              hipStream_t stream) {
    const float* style = (const float*)d_in[0];   // [32, 512]
    const float* U     = (const float*)d_in[1];   // [64, 64, 32, 512]
    const float* L     = (const float*)d_in[2];   // [512]
    const float* mu    = (const float*)d_in[3];   // [64, 64, 32]
    float* out = (float*)d_out;                   // [32, 64, 64, 32]
    float* scaledT = (float*)d_ws;                // 512*32 floats = 64 KiB

    scale_kernel<<<64, 256, 0, stream>>>(style, L, scaledT);
    eigen_kernel<<<ROWS / BM, 256, 0, stream>>>(U, mu, scaledT, out);
}